// Round 12
// baseline (1338.304 us; speedup 1.0000x reference)
//
#include <hip/hip_runtime.h>
#include <hip/hip_bf16.h>

#define PTS 8192
#define NSPLIT 8

// ---------------- top-16 (smallest) maintenance, fully static indexing ----------------
__device__ __forceinline__ void top_init(float (&bd)[16], int (&bi)[16]) {
#pragma unroll
  for (int t = 0; t < 16; ++t) { bd[t] = 3e38f; bi[t] = 0; }
}

// sorted ascending; bd[15] is current worst
__device__ __forceinline__ void top_insert(float (&bd)[16], int (&bi)[16], float d, int j) {
  if (d < bd[15]) {
#pragma unroll
    for (int t = 15; t >= 0; --t) {
      bool c  = d < bd[t];
      bool cp = (t > 0) ? (d < bd[t - 1]) : false;
      float nd = cp ? bd[t - 1] : d;
      int   ni = cp ? bi[t - 1] : j;
      if (c) { bd[t] = nd; bi[t] = ni; }
    }
  }
}

// ---------------- squared norms ----------------
__global__ void sqnorm_kernel(const float* __restrict__ h, float* __restrict__ sq, int C) {
  int i = blockIdx.x * 256 + threadIdx.x;
  if (i >= PTS) return;
  const float* r = h + (size_t)i * C;
  float s = 0.f;
  if ((C & 3) == 0) {
    for (int k = 0; k < C; k += 4) {
      float4 v = *(const float4*)(r + k);
      s += v.x * v.x + v.y * v.y + v.z * v.z + v.w * v.w;
    }
  } else {
    for (int k = 0; k < C; ++k) s += r[k] * r[k];
  }
  sq[i] = s;
}

// ---------------- fused pairwise-distance + per-row top-16 ----------------
// grid = 1024 blocks of 256 thr (4 waves). slice = b&7 (XCD-affine), row-tile = b>>3 (64 rows).
// Tile: 64 rows x 128 cols. Micro-tile 4x8 with SPLIT columns: thread covers cols
// {tx*4..+3} and {64+tx*4..+3} -> per k: 3 conflict-free ds_read_b128 + 32 FMA.
// A-tile (64 x C) RESIDENT [k][64] (32 KB @C=128). S (32 KB) = B dbuf (2 x [32][128])
// / D2 (64x128, aliases full S) / merge buffers. r9-proven barrier schedule B1..B5.
template <int C>
__global__ __launch_bounds__(256) void knn_kernel(const float* __restrict__ H,
                                                  const float* __restrict__ sq,
                                                  float* __restrict__ pd,
                                                  int* __restrict__ pi) {
  constexpr int KC = (C < 32) ? C : 32;      // k-chunk
  constexpr int NC = C / KC;                 // chunks per col tile: 1,2,4
  constexpr int TT = (PTS / NSPLIT) / 128;   // 8 column tiles per block
  constexpr int N  = TT * NC;                // total chunks

  __shared__ __align__(128) float AsF[C * 64];      // [k][row64], resident
  __shared__ __align__(128) float S[2 * 32 * 128];  // 32 KB: B halves / D2 / merge

  const int tid  = threadIdx.x;
  const int b    = blockIdx.x;
  const int sy   = b & 7;                    // candidate slice (XCD-affine)
  const int sx   = b >> 3;                   // row tile
  const int row0 = sx * 64;
  const int cb   = sy * (PTS / NSPLIT);
  const int tx = tid & 15, ty = tid >> 4;    // micro-tile: rows ty*4.., cols tx*4 & 64+tx*4
  const int r_ = tid & 63, g_ = tid >> 6;    // scan/merge: lane=row, wave=32-col group

  // ---- stage A (C x 64) once, resident, layout [k][row] ----
  if constexpr (C >= 32) {
    const int r = tid & 63, h = tid >> 6;    // 4 threads per row
#pragma unroll
    for (int j = 0; j < C / 16; ++j) {
      int q = h * (C / 16) + j;
      float4 v = *(const float4*)(H + (size_t)(row0 + r) * C + q * 4);
      float vv[4] = {v.x, v.y, v.z, v.w};
#pragma unroll
      for (int e = 0; e < 4; ++e)
        AsF[(q * 4 + e) * 64 + r] = vv[e];
    }
  } else {
    if (tid < 16 * C) {                      // 48 threads x float4 = 192 floats
      float4 v = *(const float4*)(H + (size_t)row0 * C + tid * 4);
      float vv[4] = {v.x, v.y, v.z, v.w};
#pragma unroll
      for (int e = 0; e < 4; ++e) {
        int gi = tid * 4 + e;
        AsF[(gi % C) * 64 + gi / C] = vv[e];
      }
    }
  }

  float sqr[4];
#pragma unroll
  for (int u = 0; u < 4; ++u) sqr[u] = sq[row0 + ty * 4 + u];

  float bd[16]; int bi[16];
  top_init(bd, bi);

  float4 st[4];
#pragma unroll
  for (int j = 0; j < 4; ++j) st[j] = make_float4(0.f, 0.f, 0.f, 0.f);

  auto stage_load = [&](int n1) {
    if constexpr (C >= 32) {
      const int c = tid & 127, kq = tid >> 7;  // column, k-half (16 k's each)
      const float* src = H + (size_t)(cb + (n1 / NC) * 128 + c) * C + (n1 % NC) * KC + kq * 16;
#pragma unroll
      for (int j = 0; j < 4; ++j) st[j] = *(const float4*)(src + j * 4);
    } else {
      if (tid < 128) {
        const float* src = H + (size_t)(cb + n1 * 128 + tid) * C;
        st[0].x = src[0]; st[0].y = src[1]; st[0].z = src[2];
      }
    }
  };
  auto stage_write = [&](int n1) {
    float* B = S + (n1 & 1) * 4096;
    if constexpr (C >= 32) {
      const int c = tid & 127, kq = tid >> 7;
#pragma unroll
      for (int j = 0; j < 4; ++j) {
        float vv[4] = {st[j].x, st[j].y, st[j].z, st[j].w};
#pragma unroll
        for (int e = 0; e < 4; ++e)
          B[(kq * 16 + j * 4 + e) * 128 + c] = vv[e];
      }
    } else {
      if (tid < 128) {
        B[0 * 128 + tid] = st[0].x;
        B[1 * 128 + tid] = st[0].y;
        B[2 * 128 + tid] = st[0].z;
      }
    }
  };

  // ---- prologue ----
  stage_load(0);
  stage_write(0);
  __syncthreads();                           // B1: half0 ready

  float acc[4][8] = {};
  for (int n = 0; n < N; ++n) {
    if (n + 1 < N) stage_load(n + 1);        // global loads in flight under compute
    const float* Bh = S + (n & 1) * 4096;
    const int kc = (n % NC) * KC;
#pragma unroll
    for (int k = 0; k < KC; ++k) {
      float4 a4  = *(const float4*)(AsF + (kc + k) * 64 + ty * 4);
      float4 b40 = *(const float4*)(Bh + k * 128 + tx * 4);
      float4 b41 = *(const float4*)(Bh + k * 128 + 64 + tx * 4);
      float a[4]  = {a4.x, a4.y, a4.z, a4.w};
      float bb[8] = {b40.x, b40.y, b40.z, b40.w, b41.x, b41.y, b41.z, b41.w};
#pragma unroll
      for (int u = 0; u < 4; ++u)
#pragma unroll
        for (int v = 0; v < 8; ++v)
          acc[u][v] += a[u] * bb[v];
    }
    if ((n % NC) == NC - 1) {                // tile boundary: D2 + scan
      const int ct = (n / NC) * 128;
      const int cbase = cb + ct;
      float sqc[8];
#pragma unroll
      for (int v = 0; v < 4; ++v) {
        sqc[v]     = sq[cbase + tx * 4 + v];
        sqc[v + 4] = sq[cbase + 64 + tx * 4 + v];
      }
      __syncthreads();                       // B2: all compute reads of S done
#pragma unroll
      for (int u = 0; u < 4; ++u) {
        int row = ty * 4 + u;
        int gr  = row0 + row;
        int sw  = (row & 7) << 2;
        float dv[8];
#pragma unroll
        for (int v = 0; v < 4; ++v) {
          float d2 = sqr[u] + sqc[v] - 2.f * acc[u][v];
          if (gr == cbase + tx * 4 + v) d2 = 3e38f;            // exclude self (lo half)
          dv[v] = d2;
          acc[u][v] = 0.f;
          float d2h = sqr[u] + sqc[v + 4] - 2.f * acc[u][v + 4];
          d2h += 0.f;
          if (gr == cbase + 64 + tx * 4 + v) d2h = 3e38f;      // exclude self (hi half)
          dv[v + 4] = d2h;
          acc[u][v + 4] = 0.f;
        }
        *(float4*)(S + row * 128 + ((tx * 4) ^ sw)) = make_float4(dv[0], dv[1], dv[2], dv[3]);
        *(float4*)(S + row * 128 + 64 + ((tx * 4) ^ sw)) = make_float4(dv[4], dv[5], dv[6], dv[7]);
      }
      __syncthreads();                       // B3: D2 complete
      // ---- scan: lane=row r_, wave=32-col group g_, vectorized mask pass ----
      const int swr = (r_ & 7) << 2;
      unsigned mask = 0;
#pragma unroll
      for (int j = 0; j < 8; ++j) {
        int c0 = g_ * 32 + j * 4;
        int off = (c0 & 64) + ((c0 & 63) ^ swr);
        float4 f = *(const float4*)(S + r_ * 128 + off);
        if (f.x < bd[15]) mask |= (1u << (j * 4 + 0));
        if (f.y < bd[15]) mask |= (1u << (j * 4 + 1));
        if (f.z < bd[15]) mask |= (1u << (j * 4 + 2));
        if (f.w < bd[15]) mask |= (1u << (j * 4 + 3));
      }
      while (mask) {                          // divergent; cost = wave max accepts
        int q = __ffs(mask) - 1;
        mask &= mask - 1;
        int cc = g_ * 32 + q;
        int off = (cc & 64) + ((cc & 63) ^ swr);
        float d = S[r_ * 128 + off];
        top_insert(bd, bi, d, cbase + cc);
      }
      __syncthreads();                       // B4: scan reads done, S reusable
    }
    if (n + 1 < N) {
      stage_write(n + 1);                    // into half((n+1)&1)
      __syncthreads();                       // B5: next half ready
    }
  }

  // ---- hierarchical merge of the 4 per-wave lists ----
  __syncthreads();
  if (g_ == 1 || g_ == 3) {
    float* base = S + (g_ == 3 ? 2048 : 0) + r_ * 32;
#pragma unroll
    for (int t = 0; t < 16; ++t) {
      int s = (t + r_) & 15;
      base[s] = bd[t];
      ((int*)base)[16 + s] = bi[t];
    }
  }
  __syncthreads();
  if (g_ == 0 || g_ == 2) {
    const float* base = S + (g_ == 2 ? 2048 : 0) + r_ * 32;
    for (int t = 0; t < 16; ++t) {
      int s = (t + r_) & 15;
      float d = base[s];
      if (d >= bd[15]) break;                // published lists sorted ascending
      top_insert(bd, bi, d, ((const int*)base)[16 + s]);
    }
  }
  __syncthreads();
  if (g_ == 2) {
    float* base = S + r_ * 32;
#pragma unroll
    for (int t = 0; t < 16; ++t) {
      int s = (t + r_) & 15;
      base[s] = bd[t];
      ((int*)base)[16 + s] = bi[t];
    }
  }
  __syncthreads();
  if (g_ == 0) {
    const float* base = S + r_ * 32;
    for (int t = 0; t < 16; ++t) {
      int s = (t + r_) & 15;
      float d = base[s];
      if (d >= bd[15]) break;
      top_insert(bd, bi, d, ((const int*)base)[16 + s]);
    }
    size_t basep = ((size_t)(row0 + r_) * NSPLIT + sy) * 16;
#pragma unroll
    for (int t = 0; t < 16; ++t) { pd[basep + t] = bd[t]; pi[basep + t] = bi[t]; }
  }
}

__global__ void knn_merge_kernel(const float* __restrict__ pd, const int* __restrict__ pi,
                                 int* __restrict__ idx) {
  int i = blockIdx.x * 256 + threadIdx.x;
  if (i >= PTS) return;
  float bd[16]; int bi[16];
  top_init(bd, bi);
  const float* d  = pd + (size_t)i * (NSPLIT * 16);
  const int*   ii = pi + (size_t)i * (NSPLIT * 16);
  for (int L = 0; L < NSPLIT; ++L) {
    for (int t = 0; t < 16; ++t) {
      float dv = d[L * 16 + t];
      if (dv >= bd[15]) break;              // sorted sublists
      top_insert(bd, bi, dv, ii[L * 16 + t]);
    }
  }
#pragma unroll
  for (int t = 0; t < 16; ++t) idx[(size_t)i * 16 + t] = bi[t];
}

// ---------------- tiled f32 GEMM computing F = A@Wt + bias (z=0) and G = A@Wb (z=1) ----------------
__global__ __launch_bounds__(256) void gemm_fg_kernel(const float* __restrict__ A,
                                                      const float* __restrict__ Wt,
                                                      const float* __restrict__ Wb,
                                                      const float* __restrict__ bias,
                                                      float* __restrict__ F, float* __restrict__ G,
                                                      int K, int N) {
  __shared__ float As[16][68];
  __shared__ float Bs[16][68];
  const int tid  = threadIdx.x;
  const int row0 = blockIdx.x * 64, col0 = blockIdx.y * 64;
  const float* B = (blockIdx.z == 0) ? Wt : Wb;
  float* O       = (blockIdx.z == 0) ? F  : G;
  const int tx = tid & 15, ty = tid >> 4;
  float acc[4][4] = {};
  for (int k0 = 0; k0 < K; k0 += 16) {
    __syncthreads();
#pragma unroll
    for (int l = 0; l < 4; ++l) {
      int rr = (tid >> 4) + l * 16, kk = tid & 15;
      As[kk][rr] = (k0 + kk < K) ? A[(size_t)(row0 + rr) * K + k0 + kk] : 0.f;
      int cc = tid & 63, k2 = (tid >> 6) + l * 4;
      Bs[k2][cc] = (k0 + k2 < K) ? B[(size_t)(k0 + k2) * N + col0 + cc] : 0.f;
    }
    __syncthreads();
#pragma unroll
    for (int k = 0; k < 16; ++k) {
      float4 a4 = *(const float4*)&As[k][ty * 4];
      float4 b4 = *(const float4*)&Bs[k][tx * 4];
      float a[4] = {a4.x, a4.y, a4.z, a4.w};
      float b[4] = {b4.x, b4.y, b4.z, b4.w};
#pragma unroll
      for (int u = 0; u < 4; ++u)
#pragma unroll
        for (int v = 0; v < 4; ++v)
          acc[u][v] += a[u] * b[v];
    }
  }
  float bv[4] = {0.f, 0.f, 0.f, 0.f};
  if (blockIdx.z == 0) {
#pragma unroll
    for (int v = 0; v < 4; ++v) bv[v] = bias[col0 + tx * 4 + v];
  }
#pragma unroll
  for (int u = 0; u < 4; ++u)
#pragma unroll
    for (int v = 0; v < 4; ++v)
      O[(size_t)(row0 + ty * 4 + u) * N + col0 + tx * 4 + v] = acc[u][v] + bv[v];
}

// ---------------- out_i = relu(F_i - G_i + max_{j in idx_i} G_j) ----------------
__global__ void gather_max_kernel(const float* __restrict__ F, const float* __restrict__ G,
                                  const int* __restrict__ idx, float* __restrict__ Ho, int Cn) {
  int t = blockIdx.x * 256 + threadIdx.x;
  int per = Cn >> 2;
  int i = t / per;
  if (i >= PTS) return;
  int c = (t - i * per) * 4;
  const int* ji = idx + (size_t)i * 16;
  float4 m = make_float4(-3e38f, -3e38f, -3e38f, -3e38f);
#pragma unroll
  for (int s = 0; s < 16; ++s) {
    float4 v = *(const float4*)(G + (size_t)ji[s] * Cn + c);
    m.x = fmaxf(m.x, v.x); m.y = fmaxf(m.y, v.y);
    m.z = fmaxf(m.z, v.z); m.w = fmaxf(m.w, v.w);
  }
  float4 gi = *(const float4*)(G + (size_t)i * Cn + c);
  float4 f  = *(const float4*)(F + (size_t)i * Cn + c);
  float4 o;
  o.x = fmaxf(f.x - gi.x + m.x, 0.f);
  o.y = fmaxf(f.y - gi.y + m.y, 0.f);
  o.z = fmaxf(f.z - gi.z + m.z, 0.f);
  o.w = fmaxf(f.w - gi.w + m.w, 0.f);
  *(float4*)(Ho + (size_t)i * Cn + c) = o;
}

// ---------------- final MLP: out = relu(h3@fW1+fb1)@fW2 + fb2 ----------------
__global__ __launch_bounds__(256) void mlp_kernel(const float* __restrict__ h3,
                                                  const float* __restrict__ fW1,
                                                  const float* __restrict__ fb1,
                                                  const float* __restrict__ fW2,
                                                  const float* __restrict__ fb2,
                                                  float* __restrict__ out) {
  __shared__ float hs[16][260];
  __shared__ float ws[64][128];
  __shared__ float red[4][8];
  const int tid = threadIdx.x;
  const int p0  = blockIdx.x * 16;
#pragma unroll
  for (int l = 0; l < 16; ++l) {
    int ii = l * 256 + tid;
    hs[ii >> 8][ii & 255] = h3[(size_t)(p0 + (ii >> 8)) * 256 + (ii & 255)];
  }
  const int c = tid & 127, half = tid >> 7;
  float acc[8];
#pragma unroll
  for (int pp = 0; pp < 8; ++pp) acc[pp] = fb1[c];
  for (int k0 = 0; k0 < 256; k0 += 64) {
    __syncthreads();
#pragma unroll
    for (int l = 0; l < 32; ++l) {
      int ii = l * 256 + tid;
      ws[ii >> 7][ii & 127] = fW1[(size_t)(k0 + (ii >> 7)) * 128 + (ii & 127)];
    }
    __syncthreads();
    for (int k = 0; k < 64; k += 4) {
      float w0 = ws[k][c], w1 = ws[k + 1][c], w2 = ws[k + 2][c], w3 = ws[k + 3][c];
#pragma unroll
      for (int pp = 0; pp < 8; ++pp) {
        float4 h4 = *(const float4*)&hs[half * 8 + pp][k0 + k];
        acc[pp] += h4.x * w0 + h4.y * w1 + h4.z * w2 + h4.w * w3;
      }
    }
  }
  float w2v = fW2[c];
  float s[8];
#pragma unroll
  for (int pp = 0; pp < 8; ++pp) s[pp] = fmaxf(acc[pp], 0.f) * w2v;
#pragma unroll
  for (int off = 32; off > 0; off >>= 1) {
#pragma unroll
    for (int pp = 0; pp < 8; ++pp) s[pp] += __shfl_down(s[pp], off);
  }
  if ((tid & 63) == 0) {
#pragma unroll
    for (int pp = 0; pp < 8; ++pp) red[tid >> 6][pp] = s[pp];
  }
  __syncthreads();
  if (tid < 16) {
    int hf = tid >> 3, pp = tid & 7;
    float v = red[hf * 2][pp] + red[hf * 2 + 1][pp] + fb2[0];
    out[p0 + hf * 8 + pp] = v;
  }
}

// ---------------- host ----------------
extern "C" void kernel_launch(void* const* d_in, const int* in_sizes, int n_in,
                              void* d_out, int out_size, void* d_ws, size_t ws_size,
                              hipStream_t stream) {
  (void)in_sizes; (void)n_in; (void)out_size; (void)ws_size;
  const float* x   = (const float*)d_in[0];
  const float* W1  = (const float*)d_in[1];
  const float* b1  = (const float*)d_in[2];
  const float* W2  = (const float*)d_in[3];
  const float* b2  = (const float*)d_in[4];
  const float* W3  = (const float*)d_in[5];
  const float* b3  = (const float*)d_in[6];
  const float* fW1 = (const float*)d_in[7];
  const float* fb1 = (const float*)d_in[8];
  const float* fW2 = (const float*)d_in[9];
  const float* fb2 = (const float*)d_in[10];

  float* w = (float*)d_ws;
  size_t o = 0;
  float* sq  = w + o; o += PTS;
  float* h1  = w + o; o += (size_t)PTS * 64;
  float* h2  = w + o; o += (size_t)PTS * 128;
  float* h3  = w + o; o += (size_t)PTS * 256;
  float* F   = w + o; o += (size_t)PTS * 256;
  float* G   = w + o; o += (size_t)PTS * 256;
  float* pd  = w + o; o += (size_t)PTS * 128;
  int*   pi  = (int*)(w + o); o += (size_t)PTS * 128;
  int*   idx = (int*)(w + o); o += (size_t)PTS * 16;

  const int KNN_GRID = (PTS / 64) * NSPLIT;  // 1024 blocks of 256 threads

  // ---- layer 1 (C=3 -> 64) ----
  sqnorm_kernel<<<PTS / 256, 256, 0, stream>>>(x, sq, 3);
  knn_kernel<3><<<KNN_GRID, 256, 0, stream>>>(x, sq, pd, pi);
  knn_merge_kernel<<<PTS / 256, 256, 0, stream>>>(pd, pi, idx);
  gemm_fg_kernel<<<dim3(PTS / 64, 1, 2), 256, 0, stream>>>(x, W1, W1 + 3 * 64, b1, F, G, 3, 64);
  gather_max_kernel<<<(PTS * 16 + 255) / 256, 256, 0, stream>>>(F, G, idx, h1, 64);

  // ---- layer 2 (C=64 -> 128) ----
  sqnorm_kernel<<<PTS / 256, 256, 0, stream>>>(h1, sq, 64);
  knn_kernel<64><<<KNN_GRID, 256, 0, stream>>>(h1, sq, pd, pi);
  knn_merge_kernel<<<PTS / 256, 256, 0, stream>>>(pd, pi, idx);
  gemm_fg_kernel<<<dim3(PTS / 64, 2, 2), 256, 0, stream>>>(h1, W2, W2 + 64 * 128, b2, F, G, 64, 128);
  gather_max_kernel<<<(PTS * 32 + 255) / 256, 256, 0, stream>>>(F, G, idx, h2, 128);

  // ---- layer 3 (C=128 -> 256) ----
  sqnorm_kernel<<<PTS / 256, 256, 0, stream>>>(h2, sq, 128);
  knn_kernel<128><<<KNN_GRID, 256, 0, stream>>>(h2, sq, pd, pi);
  knn_merge_kernel<<<PTS / 256, 256, 0, stream>>>(pd, pi, idx);
  gemm_fg_kernel<<<dim3(PTS / 64, 4, 2), 256, 0, stream>>>(h2, W3, W3 + 128 * 256, b3, F, G, 128, 256);
  gather_max_kernel<<<(PTS * 64 + 255) / 256, 256, 0, stream>>>(F, G, idx, h3, 256);

  // ---- final MLP ----
  mlp_kernel<<<PTS / 16, 256, 0, stream>>>(h3, fW1, fb1, fW2, fb2, (float*)d_out);
}

// Round 13
// 959.225 us; speedup vs baseline: 1.3952x; 1.3952x over previous
//
#include <hip/hip_runtime.h>
#include <hip/hip_bf16.h>

#define PTS 8192
#define NSPLIT 8

// ---------------- top-16 (smallest) maintenance, fully static indexing ----------------
__device__ __forceinline__ void top_init(float (&bd)[16], int (&bi)[16]) {
#pragma unroll
  for (int t = 0; t < 16; ++t) { bd[t] = 3e38f; bi[t] = 0; }
}

// sorted ascending; bd[15] is current worst
__device__ __forceinline__ void top_insert(float (&bd)[16], int (&bi)[16], float d, int j) {
  if (d < bd[15]) {
#pragma unroll
    for (int t = 15; t >= 0; --t) {
      bool c  = d < bd[t];
      bool cp = (t > 0) ? (d < bd[t - 1]) : false;
      float nd = cp ? bd[t - 1] : d;
      int   ni = cp ? bi[t - 1] : j;
      if (c) { bd[t] = nd; bi[t] = ni; }
    }
  }
}

// ---------------- squared norms ----------------
__global__ void sqnorm_kernel(const float* __restrict__ h, float* __restrict__ sq, int C) {
  int i = blockIdx.x * 256 + threadIdx.x;
  if (i >= PTS) return;
  const float* r = h + (size_t)i * C;
  float s = 0.f;
  if ((C & 3) == 0) {
    for (int k = 0; k < C; k += 4) {
      float4 v = *(const float4*)(r + k);
      s += v.x * v.x + v.y * v.y + v.z * v.z + v.w * v.w;
    }
  } else {
    for (int k = 0; k < C; ++k) s += r[k] * r[k];
  }
  sq[i] = s;
}

// ---------------- fused pairwise-distance + per-row top-16 ----------------
// grid = 2048 blocks of 128 thr (2 waves). slice = b&7 (XCD-affine), row-tile = b>>3 (32 rows).
// Tile: 32 rows x 64 cols, micro 4x4. A-tile (32 x C) RESIDENT [k][32] (16 KB @C=128).
// S (8 KB) = KC=16 double-buffered B chunks (2 x [16][64] = EXACTLY the D2 32x64 region,
// perfect alias) / D2 (row-XOR swizzled) / merge buffers. r9-proven schedule B1..B5.
// LDS total 24 KB @C=128 -> ~6 blocks/CU (12 waves). Density = r9 (2 reads + 16 FMA per k).
template <int C>
__global__ __launch_bounds__(128) void knn_kernel(const float* __restrict__ H,
                                                  const float* __restrict__ sq,
                                                  float* __restrict__ pd,
                                                  int* __restrict__ pi) {
  constexpr int KC = (C < 16) ? C : 16;      // k-chunk
  constexpr int NC = C / KC;                 // chunks per col tile: 1, 4, 8
  constexpr int TT = (PTS / NSPLIT) / 64;    // 16 column tiles per block
  constexpr int N  = TT * NC;                // total chunks

  __shared__ __align__(128) float AsF[C * 32];   // [k][row32], resident
  __shared__ __align__(128) float S[2048];       // 8 KB: B dbuf (2x[16][64]) / D2 / merge

  const int tid  = threadIdx.x;
  const int b    = blockIdx.x;
  const int sy   = b & 7;                    // candidate slice (XCD-affine)
  const int sx   = b >> 3;                   // row tile
  const int row0 = sx * 32;
  const int cb   = sy * (PTS / NSPLIT);
  const int tx = tid & 15, ty = tid >> 4;    // micro-tile: cols tx*4.., rows ty*4.. (ty 0..7)
  const int r_ = tid & 31, g4 = tid >> 5;    // scan: lane-row, col-group of 16 (0..3)
  const int l_ = tid & 63, w_ = tid >> 6;    // lane, wave

  // ---- stage A (C x 32) once, resident, layout [k][row] ----
  if constexpr (C >= 16) {
    const int r = tid >> 2, q0 = tid & 3;    // 4 threads per row
#pragma unroll
    for (int j = 0; j < C / 16; ++j) {
      int q = q0 + j * 4;
      float4 v = *(const float4*)(H + (size_t)(row0 + r) * C + q * 4);
      float vv[4] = {v.x, v.y, v.z, v.w};
#pragma unroll
      for (int e = 0; e < 4; ++e)
        AsF[(q * 4 + e) * 32 + r] = vv[e];
    }
  } else {
    if (tid < 32 * C) {
      int rr = tid & 31, kk = tid >> 5;
      AsF[kk * 32 + rr] = H[(size_t)(row0 + rr) * C + kk];
    }
  }

  float sqr[4];
#pragma unroll
  for (int u = 0; u < 4; ++u) sqr[u] = sq[row0 + ty * 4 + u];

  float bd[16]; int bi[16];
  top_init(bd, bi);

  float4 st0 = make_float4(0.f, 0.f, 0.f, 0.f);
  float4 st1 = make_float4(0.f, 0.f, 0.f, 0.f);
  auto stage_load = [&](int n1) {
    if constexpr (C >= 16) {
      const int c = tid & 63, kq = tid >> 6;     // col, k-half (8 k's each)
      const float* src = H + (size_t)(cb + (n1 / NC) * 64 + c) * C + (n1 % NC) * KC + kq * 8;
      st0 = *(const float4*)(src);
      st1 = *(const float4*)(src + 4);
    } else {
      if (tid < 64) {
        const float* src = H + (size_t)(cb + n1 * 64 + tid) * C;
        st0.x = src[0]; st0.y = src[1]; st0.z = src[2];
      }
    }
  };
  auto stage_write = [&](int n1) {
    float* B = S + (n1 & 1) * 1024;
    if constexpr (C >= 16) {
      const int c = tid & 63, kq = tid >> 6;
      float v0[4] = {st0.x, st0.y, st0.z, st0.w};
      float v1[4] = {st1.x, st1.y, st1.z, st1.w};
#pragma unroll
      for (int e = 0; e < 4; ++e) {
        B[(kq * 8 + e) * 64 + c]     = v0[e];    // per instr: 64 lanes, one k-plane, cols 0..63 (free)
        B[(kq * 8 + 4 + e) * 64 + c] = v1[e];
      }
    } else {
      if (tid < 64) {
        B[0 * 64 + tid] = st0.x;
        B[1 * 64 + tid] = st0.y;
        B[2 * 64 + tid] = st0.z;
      }
    }
  };

  // ---- prologue ----
  stage_load(0);
  stage_write(0);
  __syncthreads();                           // B1: half0 ready

  float acc[4][4] = {};
  for (int n = 0; n < N; ++n) {
    if (n + 1 < N) stage_load(n + 1);        // global loads in flight under compute
    const float* Bh = S + (n & 1) * 1024;
    const int kc = (n % NC) * KC;
#pragma unroll
    for (int k = 0; k < KC; ++k) {
      float4 a4 = *(const float4*)(AsF + (kc + k) * 32 + ty * 4);   // 8-way broadcast: free
      float4 b4 = *(const float4*)(Bh + k * 64 + tx * 4);           // 2-way: free
      float a[4]  = {a4.x, a4.y, a4.z, a4.w};
      float bb[4] = {b4.x, b4.y, b4.z, b4.w};
#pragma unroll
      for (int u = 0; u < 4; ++u)
#pragma unroll
        for (int v = 0; v < 4; ++v)
          acc[u][v] += a[u] * bb[v];
    }
    if ((n % NC) == NC - 1) {                // tile boundary: D2 + scan
      const int ct = (n / NC) * 64;
      const int cbase = cb + ct;
      float sqc[4];
#pragma unroll
      for (int v = 0; v < 4; ++v) sqc[v] = sq[cbase + tx * 4 + v];
      __syncthreads();                       // B2: all compute reads of S done
#pragma unroll
      for (int u = 0; u < 4; ++u) {
        int row = ty * 4 + u;
        int gr  = row0 + row;
        int sw  = (row & 7) << 2;
        float dv[4];
#pragma unroll
        for (int v = 0; v < 4; ++v) {
          float d2 = sqr[u] + sqc[v] - 2.f * acc[u][v];
          if (gr == cbase + tx * 4 + v) d2 = 3e38f;   // exclude self
          dv[v] = d2;
          acc[u][v] = 0.f;
        }
        *(float4*)(S + row * 64 + ((tx * 4) ^ sw)) = make_float4(dv[0], dv[1], dv[2], dv[3]);
      }
      __syncthreads();                       // B3: D2 complete
      // ---- scan: lane-row r_, 16-col group g4, vectorized mask pass ----
      const int swr = (r_ & 7) << 2;
      unsigned mask = 0;
#pragma unroll
      for (int j = 0; j < 4; ++j) {
        float4 f = *(const float4*)(S + r_ * 64 + ((g4 * 16 + j * 4) ^ swr));
        if (f.x < bd[15]) mask |= (1u << (j * 4 + 0));
        if (f.y < bd[15]) mask |= (1u << (j * 4 + 1));
        if (f.z < bd[15]) mask |= (1u << (j * 4 + 2));
        if (f.w < bd[15]) mask |= (1u << (j * 4 + 3));
      }
      while (mask) {                          // divergent; cost = wave max accepts
        int q = __ffs(mask) - 1;
        mask &= mask - 1;
        int cc = g4 * 16 + q;
        float d = S[r_ * 64 + (cc ^ swr)];
        top_insert(bd, bi, d, cbase + cc);
      }
      __syncthreads();                       // B4: scan reads done, S reusable
    }
    if (n + 1 < N) {
      stage_write(n + 1);                    // into half((n+1)&1)
      __syncthreads();                       // B5: next half ready
    }
  }

  // ---- merge: in-wave partner (lane^32 = same row, adjacent col-group) ----
  for (int t = 0; t < 16; ++t) {
    float d = __shfl(bd[t], (l_ & 31) + 32);
    int   i = __shfl(bi[t], (l_ & 31) + 32);
    unsigned long long m = __ballot((l_ < 32) && (d < bd[15]));
    if (!m) break;
    if (l_ < 32) top_insert(bd, bi, d, i);
  }
  // ---- cross-wave: wave 1 publishes sorted list, wave 0 merges ----
  __syncthreads();
  if (w_ == 1 && l_ < 32) {
    float* base = S + r_ * 32;
#pragma unroll
    for (int t = 0; t < 16; ++t) {
      int s = (t + r_) & 15;
      base[s] = bd[t];
      ((int*)base)[16 + s] = bi[t];
    }
  }
  __syncthreads();
  if (w_ == 0 && l_ < 32) {
    const float* base = S + r_ * 32;
    for (int t = 0; t < 16; ++t) {
      int s = (t + r_) & 15;
      float d = base[s];
      if (d >= bd[15]) break;                // published list sorted ascending
      top_insert(bd, bi, d, ((const int*)base)[16 + s]);
    }
    size_t basep = ((size_t)(row0 + r_) * NSPLIT + sy) * 16;
#pragma unroll
    for (int t = 0; t < 16; ++t) { pd[basep + t] = bd[t]; pi[basep + t] = bi[t]; }
  }
}

__global__ void knn_merge_kernel(const float* __restrict__ pd, const int* __restrict__ pi,
                                 int* __restrict__ idx) {
  int i = blockIdx.x * 256 + threadIdx.x;
  if (i >= PTS) return;
  float bd[16]; int bi[16];
  top_init(bd, bi);
  const float* d  = pd + (size_t)i * (NSPLIT * 16);
  const int*   ii = pi + (size_t)i * (NSPLIT * 16);
  for (int L = 0; L < NSPLIT; ++L) {
    for (int t = 0; t < 16; ++t) {
      float dv = d[L * 16 + t];
      if (dv >= bd[15]) break;              // sorted sublists
      top_insert(bd, bi, dv, ii[L * 16 + t]);
    }
  }
#pragma unroll
  for (int t = 0; t < 16; ++t) idx[(size_t)i * 16 + t] = bi[t];
}

// ---------------- tiled f32 GEMM computing F = A@Wt + bias (z=0) and G = A@Wb (z=1) ----------------
__global__ __launch_bounds__(256) void gemm_fg_kernel(const float* __restrict__ A,
                                                      const float* __restrict__ Wt,
                                                      const float* __restrict__ Wb,
                                                      const float* __restrict__ bias,
                                                      float* __restrict__ F, float* __restrict__ G,
                                                      int K, int N) {
  __shared__ float As[16][68];
  __shared__ float Bs[16][68];
  const int tid  = threadIdx.x;
  const int row0 = blockIdx.x * 64, col0 = blockIdx.y * 64;
  const float* B = (blockIdx.z == 0) ? Wt : Wb;
  float* O       = (blockIdx.z == 0) ? F  : G;
  const int tx = tid & 15, ty = tid >> 4;
  float acc[4][4] = {};
  for (int k0 = 0; k0 < K; k0 += 16) {
    __syncthreads();
#pragma unroll
    for (int l = 0; l < 4; ++l) {
      int rr = (tid >> 4) + l * 16, kk = tid & 15;
      As[kk][rr] = (k0 + kk < K) ? A[(size_t)(row0 + rr) * K + k0 + kk] : 0.f;
      int cc = tid & 63, k2 = (tid >> 6) + l * 4;
      Bs[k2][cc] = (k0 + k2 < K) ? B[(size_t)(k0 + k2) * N + col0 + cc] : 0.f;
    }
    __syncthreads();
#pragma unroll
    for (int k = 0; k < 16; ++k) {
      float4 a4 = *(const float4*)&As[k][ty * 4];
      float4 b4 = *(const float4*)&Bs[k][tx * 4];
      float a[4] = {a4.x, a4.y, a4.z, a4.w};
      float b[4] = {b4.x, b4.y, b4.z, b4.w};
#pragma unroll
      for (int u = 0; u < 4; ++u)
#pragma unroll
        for (int v = 0; v < 4; ++v)
          acc[u][v] += a[u] * b[v];
    }
  }
  float bv[4] = {0.f, 0.f, 0.f, 0.f};
  if (blockIdx.z == 0) {
#pragma unroll
    for (int v = 0; v < 4; ++v) bv[v] = bias[col0 + tx * 4 + v];
  }
#pragma unroll
  for (int u = 0; u < 4; ++u)
#pragma unroll
    for (int v = 0; v < 4; ++v)
      O[(size_t)(row0 + ty * 4 + u) * N + col0 + tx * 4 + v] = acc[u][v] + bv[v];
}

// ---------------- out_i = relu(F_i - G_i + max_{j in idx_i} G_j) ----------------
__global__ void gather_max_kernel(const float* __restrict__ F, const float* __restrict__ G,
                                  const int* __restrict__ idx, float* __restrict__ Ho, int Cn) {
  int t = blockIdx.x * 256 + threadIdx.x;
  int per = Cn >> 2;
  int i = t / per;
  if (i >= PTS) return;
  int c = (t - i * per) * 4;
  const int* ji = idx + (size_t)i * 16;
  float4 m = make_float4(-3e38f, -3e38f, -3e38f, -3e38f);
#pragma unroll
  for (int s = 0; s < 16; ++s) {
    float4 v = *(const float4*)(G + (size_t)ji[s] * Cn + c);
    m.x = fmaxf(m.x, v.x); m.y = fmaxf(m.y, v.y);
    m.z = fmaxf(m.z, v.z); m.w = fmaxf(m.w, v.w);
  }
  float4 gi = *(const float4*)(G + (size_t)i * Cn + c);
  float4 f  = *(const float4*)(F + (size_t)i * Cn + c);
  float4 o;
  o.x = fmaxf(f.x - gi.x + m.x, 0.f);
  o.y = fmaxf(f.y - gi.y + m.y, 0.f);
  o.z = fmaxf(f.z - gi.z + m.z, 0.f);
  o.w = fmaxf(f.w - gi.w + m.w, 0.f);
  *(float4*)(Ho + (size_t)i * Cn + c) = o;
}

// ---------------- final MLP: out = relu(h3@fW1+fb1)@fW2 + fb2 ----------------
__global__ __launch_bounds__(256) void mlp_kernel(const float* __restrict__ h3,
                                                  const float* __restrict__ fW1,
                                                  const float* __restrict__ fb1,
                                                  const float* __restrict__ fW2,
                                                  const float* __restrict__ fb2,
                                                  float* __restrict__ out) {
  __shared__ float hs[16][260];
  __shared__ float ws[64][128];
  __shared__ float red[4][8];
  const int tid = threadIdx.x;
  const int p0  = blockIdx.x * 16;
#pragma unroll
  for (int l = 0; l < 16; ++l) {
    int ii = l * 256 + tid;
    hs[ii >> 8][ii & 255] = h3[(size_t)(p0 + (ii >> 8)) * 256 + (ii & 255)];
  }
  const int c = tid & 127, half = tid >> 7;
  float acc[8];
#pragma unroll
  for (int pp = 0; pp < 8; ++pp) acc[pp] = fb1[c];
  for (int k0 = 0; k0 < 256; k0 += 64) {
    __syncthreads();
#pragma unroll
    for (int l = 0; l < 32; ++l) {
      int ii = l * 256 + tid;
      ws[ii >> 7][ii & 127] = fW1[(size_t)(k0 + (ii >> 7)) * 128 + (ii & 127)];
    }
    __syncthreads();
    for (int k = 0; k < 64; k += 4) {
      float w0 = ws[k][c], w1 = ws[k + 1][c], w2 = ws[k + 2][c], w3 = ws[k + 3][c];
#pragma unroll
      for (int pp = 0; pp < 8; ++pp) {
        float4 h4 = *(const float4*)&hs[half * 8 + pp][k0 + k];
        acc[pp] += h4.x * w0 + h4.y * w1 + h4.z * w2 + h4.w * w3;
      }
    }
  }
  float w2v = fW2[c];
  float s[8];
#pragma unroll
  for (int pp = 0; pp < 8; ++pp) s[pp] = fmaxf(acc[pp], 0.f) * w2v;
#pragma unroll
  for (int off = 32; off > 0; off >>= 1) {
#pragma unroll
    for (int pp = 0; pp < 8; ++pp) s[pp] += __shfl_down(s[pp], off);
  }
  if ((tid & 63) == 0) {
#pragma unroll
    for (int pp = 0; pp < 8; ++pp) red[tid >> 6][pp] = s[pp];
  }
  __syncthreads();
  if (tid < 16) {
    int hf = tid >> 3, pp = tid & 7;
    float v = red[hf * 2][pp] + red[hf * 2 + 1][pp] + fb2[0];
    out[p0 + hf * 8 + pp] = v;
  }
}

// ---------------- host ----------------
extern "C" void kernel_launch(void* const* d_in, const int* in_sizes, int n_in,
                              void* d_out, int out_size, void* d_ws, size_t ws_size,
                              hipStream_t stream) {
  (void)in_sizes; (void)n_in; (void)out_size; (void)ws_size;
  const float* x   = (const float*)d_in[0];
  const float* W1  = (const float*)d_in[1];
  const float* b1  = (const float*)d_in[2];
  const float* W2  = (const float*)d_in[3];
  const float* b2  = (const float*)d_in[4];
  const float* W3  = (const float*)d_in[5];
  const float* b3  = (const float*)d_in[6];
  const float* fW1 = (const float*)d_in[7];
  const float* fb1 = (const float*)d_in[8];
  const float* fW2 = (const float*)d_in[9];
  const float* fb2 = (const float*)d_in[10];

  float* w = (float*)d_ws;
  size_t o = 0;
  float* sq  = w + o; o += PTS;
  float* h1  = w + o; o += (size_t)PTS * 64;
  float* h2  = w + o; o += (size_t)PTS * 128;
  float* h3  = w + o; o += (size_t)PTS * 256;
  float* F   = w + o; o += (size_t)PTS * 256;
  float* G   = w + o; o += (size_t)PTS * 256;
  float* pd  = w + o; o += (size_t)PTS * 128;
  int*   pi  = (int*)(w + o); o += (size_t)PTS * 128;
  int*   idx = (int*)(w + o); o += (size_t)PTS * 16;

  const int KNN_GRID = (PTS / 32) * NSPLIT;  // 2048 blocks of 128 threads

  // ---- layer 1 (C=3 -> 64) ----
  sqnorm_kernel<<<PTS / 256, 256, 0, stream>>>(x, sq, 3);
  knn_kernel<3><<<KNN_GRID, 128, 0, stream>>>(x, sq, pd, pi);
  knn_merge_kernel<<<PTS / 256, 256, 0, stream>>>(pd, pi, idx);
  gemm_fg_kernel<<<dim3(PTS / 64, 1, 2), 256, 0, stream>>>(x, W1, W1 + 3 * 64, b1, F, G, 3, 64);
  gather_max_kernel<<<(PTS * 16 + 255) / 256, 256, 0, stream>>>(F, G, idx, h1, 64);

  // ---- layer 2 (C=64 -> 128) ----
  sqnorm_kernel<<<PTS / 256, 256, 0, stream>>>(h1, sq, 64);
  knn_kernel<64><<<KNN_GRID, 128, 0, stream>>>(h1, sq, pd, pi);
  knn_merge_kernel<<<PTS / 256, 256, 0, stream>>>(pd, pi, idx);
  gemm_fg_kernel<<<dim3(PTS / 64, 2, 2), 256, 0, stream>>>(h1, W2, W2 + 64 * 128, b2, F, G, 64, 128);
  gather_max_kernel<<<(PTS * 32 + 255) / 256, 256, 0, stream>>>(F, G, idx, h2, 128);

  // ---- layer 3 (C=128 -> 256) ----
  sqnorm_kernel<<<PTS / 256, 256, 0, stream>>>(h2, sq, 128);
  knn_kernel<128><<<KNN_GRID, 128, 0, stream>>>(h2, sq, pd, pi);
  knn_merge_kernel<<<PTS / 256, 256, 0, stream>>>(pd, pi, idx);
  gemm_fg_kernel<<<dim3(PTS / 64, 4, 2), 256, 0, stream>>>(h2, W3, W3 + 128 * 256, b3, F, G, 128, 256);
  gather_max_kernel<<<(PTS * 64 + 255) / 256, 256, 0, stream>>>(F, G, idx, h3, 256);

  // ---- final MLP ----
  mlp_kernel<<<PTS / 16, 256, 0, stream>>>(h3, fW1, fb1, fW2, fb2, (float*)d_out);
}